// Round 5
// baseline (317.917 us; speedup 1.0000x reference)
//
#include <hip/hip_runtime.h>
#include <stdint.h>

typedef float  f32x4  __attribute__((ext_vector_type(4)));
typedef float  float4v __attribute__((ext_vector_type(4)));
typedef int    i32x4  __attribute__((ext_vector_type(4)));
typedef int    i32x8  __attribute__((ext_vector_type(8)));
typedef unsigned int u32x4 __attribute__((ext_vector_type(4)));

#define BM 256
#define BN 256
#define BKB 128   // fp8 bytes (=elements) per K-tile

// ---- f32 (pre-clamped to [-448,448]) -> OCP e4m3fn byte, RNE (matches ml_dtypes) ----
__device__ __forceinline__ unsigned f32_to_e4m3(float t) {
    unsigned u = __float_as_uint(t);
    unsigned s = (u >> 24) & 0x80u;
    float ax = fabsf(t);
    if (ax < 0.015625f) {                      // subnormal grid 2^-9
        int m = (int)rintf(ax * 512.0f);
        return s | (unsigned)m;
    }
    unsigned au = u & 0x7fffffffu;
    unsigned r = au + 0x7FFFFu + ((au >> 20) & 1u);   // RNE into top-3 mantissa bits
    return s | (((r >> 23) - 120u) << 3) | ((r >> 20) & 7u);
}

__global__ void quant_x_kernel(const float4v* __restrict__ x, u32x4* __restrict__ out,
                               const float* __restrict__ in_scale, long n16) {
    const float inv = 1.0f / in_scale[0];
    long i = (long)blockIdx.x * blockDim.x + threadIdx.x;
    const long stride = (long)gridDim.x * blockDim.x;
    for (; i < n16; i += stride) {
        u32x4 q;
#pragma unroll
        for (int j = 0; j < 4; ++j) {
            float4v v = x[i * 4 + j];
            unsigned p = 0;
#pragma unroll
            for (int e = 0; e < 4; ++e) {
                float t = fminf(fmaxf(v[e] * inv, -448.0f), 448.0f);
                p |= f32_to_e4m3(t) << (8 * e);
            }
            q[j] = p;
        }
        out[i] = q;
    }
}

__global__ void quant_w_kernel(const float4v* __restrict__ w, u32x4* __restrict__ out, long n16) {
    long i = (long)blockIdx.x * blockDim.x + threadIdx.x;
    const long stride = (long)gridDim.x * blockDim.x;
    for (; i < n16; i += stride) {
        u32x4 q;
#pragma unroll
        for (int j = 0; j < 4; ++j) {
            float4v v = w[i * 4 + j];
            unsigned p = 0;
#pragma unroll
            for (int e = 0; e < 4; ++e) p |= f32_to_e4m3(v[e]) << (8 * e);
            q[j] = p;
        }
        out[i] = q;
    }
}

// ================= 256x256 T3-minimum pipelined MX-fp8 GEMM =================
// 8 waves (2M x 4N), per-wave 128x64 output. Double-buffered LDS (128 KB).
// Stage tile t+1 BEFORE computing tile t; one __syncthreads per iter
// (its vmcnt(0) drains the prefetch that had a full compute phase to land).

__global__ __launch_bounds__(512, 2) void gemm_kernel(
    const unsigned char* __restrict__ A,   // [M,K] e4m3 bytes
    const unsigned char* __restrict__ W,   // [N,K] e4m3 bytes
    const float* __restrict__ bias,
    const float* __restrict__ in_scale,
    const float* __restrict__ w_scale,
    float* __restrict__ C, int M, int N, int K)
{
    __shared__ __align__(16) unsigned char sA0[BM * BKB];  // 32 KB each
    __shared__ __align__(16) unsigned char sB0[BN * BKB];
    __shared__ __align__(16) unsigned char sA1[BM * BKB];
    __shared__ __align__(16) unsigned char sB1[BN * BKB];

    const int tid  = threadIdx.x;
    const int wave = tid >> 6;     // 0..7
    const int lane = tid & 63;
    const int wr   = wave >> 2;    // 0..1  (M half)
    const int wc   = wave & 3;     // 0..3  (N quarter)

    // XCD-aware bijective swizzle (512 % 8 == 0)
    const int nwg = gridDim.x;
    int bid = blockIdx.x, wgid;
    if ((nwg & 7) == 0) { const int cpx = nwg >> 3; wgid = (bid & 7) * cpx + (bid >> 3); }
    else wgid = bid;
    const int ntn  = N / BN;
    const int brow = (wgid / ntn) * BM;
    const int bcol = (wgid % ntn) * BN;

    // staging: 32 chunks of 1KB per operand (8 rows x 128B); wave w stages chunks 4w..4w+3
    // phys 16B-slot (lane&7) holds logical slot (lane&7)^(lane>>3)  (pre-swizzled source)
    const int rowInChunk = lane >> 3;
    const int slotLog    = (lane & 7) ^ rowInChunk;

    f32x4 acc[8][4];
#pragma unroll
    for (int i = 0; i < 8; ++i)
#pragma unroll
        for (int j = 0; j < 4; ++j) { f32x4 z = {0.f,0.f,0.f,0.f}; acc[i][j] = z; }

    const int g = lane >> 4;       // k-group: lane covers k bytes [g*32, g*32+32)

    const int NT = K / BKB;        // 32

    // ---- staging macro: issue 8 global_load_lds for tile t into (dA,dB) ----
#define STAGE(dA, dB, t)                                                          \
    {                                                                             \
        const int kt = (t) * BKB;                                                 \
        _Pragma("unroll")                                                         \
        for (int c = 0; c < 4; ++c) {                                             \
            const int chunk = wave * 4 + c;                                       \
            const int row   = chunk * 8 + rowInChunk;                             \
            const unsigned char* ga = A + (long)(brow + row) * K + kt + slotLog * 16; \
            const unsigned char* gb = W + (long)(bcol + row) * K + kt + slotLog * 16; \
            __builtin_amdgcn_global_load_lds(                                     \
                (const __attribute__((address_space(1))) unsigned int*)ga,        \
                (__attribute__((address_space(3))) unsigned int*)((dA) + chunk * 1024), 16, 0, 0); \
            __builtin_amdgcn_global_load_lds(                                     \
                (const __attribute__((address_space(1))) unsigned int*)gb,        \
                (__attribute__((address_space(3))) unsigned int*)((dB) + chunk * 1024), 16, 0, 0); \
        }                                                                         \
    }

    // ---- compute macro: 32 MFMAs on (srcA, srcB) ----
#define COMPUTE(srcA, srcB)                                                       \
    {                                                                             \
        i32x8 bfr[4];                                                             \
        _Pragma("unroll")                                                         \
        for (int ni = 0; ni < 4; ++ni) {                                          \
            const int row = wc * 64 + ni * 16 + (lane & 15);                      \
            const int sw  = row & 7;                                              \
            const int s0  = (g << 1) ^ sw;                                        \
            i32x4 lo = *(const i32x4*)((srcB) + row * 128 + s0 * 16);             \
            i32x4 hi = *(const i32x4*)((srcB) + row * 128 + (s0 ^ 1) * 16);       \
            i32x8 tv;                                                             \
            tv[0]=lo[0]; tv[1]=lo[1]; tv[2]=lo[2]; tv[3]=lo[3];                   \
            tv[4]=hi[0]; tv[5]=hi[1]; tv[6]=hi[2]; tv[7]=hi[3];                   \
            bfr[ni] = tv;                                                         \
        }                                                                         \
        _Pragma("unroll")                                                         \
        for (int mi = 0; mi < 8; ++mi) {                                          \
            const int row = wr * 128 + mi * 16 + (lane & 15);                     \
            const int sw  = row & 7;                                              \
            const int s0  = (g << 1) ^ sw;                                        \
            i32x4 lo = *(const i32x4*)((srcA) + row * 128 + s0 * 16);             \
            i32x4 hi = *(const i32x4*)((srcA) + row * 128 + (s0 ^ 1) * 16);       \
            i32x8 av;                                                             \
            av[0]=lo[0]; av[1]=lo[1]; av[2]=lo[2]; av[3]=lo[3];                   \
            av[4]=hi[0]; av[5]=hi[1]; av[6]=hi[2]; av[7]=hi[3];                   \
            _Pragma("unroll")                                                     \
            for (int ni = 0; ni < 4; ++ni)                                        \
                acc[mi][ni] = __builtin_amdgcn_mfma_scale_f32_16x16x128_f8f6f4(   \
                    av, bfr[ni], acc[mi][ni],                                     \
                    0, 0, 0, 0x7F7F7F7F, 0, 0x7F7F7F7F);                          \
        }                                                                         \
    }

    // prologue: tile 0 -> buf0
    STAGE(sA0, sB0, 0);
    __syncthreads();                       // drain tile0 loads

    int t = 0;
    for (; t + 2 <= NT; t += 2) {
        STAGE(sA1, sB1, t + 1);            // prefetch odd tile while computing even
        COMPUTE(sA0, sB0);
        __syncthreads();                   // vmcnt(0): odd-tile loads landed; guard buf0 rewrite
        if (t + 2 < NT) STAGE(sA0, sB0, t + 2);
        COMPUTE(sA1, sB1);
        __syncthreads();
    }
    if (t < NT) {                          // odd NT tail (not hit for K=4096)
        COMPUTE(sA0, sB0);
        __syncthreads();
    }
#undef STAGE
#undef COMPUTE

    // epilogue: out = acc * (s_in*s_w) + bias   (C/D: col=lane&15, row=(lane>>4)*4+r)
    const float sc = in_scale[0] * w_scale[0];
#pragma unroll
    for (int ni = 0; ni < 4; ++ni) {
        const int n   = bcol + wc * 64 + ni * 16 + (lane & 15);
        const float bv = bias[n];
#pragma unroll
        for (int mi = 0; mi < 8; ++mi) {
            const int m0 = brow + wr * 128 + mi * 16 + ((lane >> 4) << 2);
#pragma unroll
            for (int r = 0; r < 4; ++r)
                C[(long)(m0 + r) * N + n] = fmaf(acc[mi][ni][r], sc, bv);
        }
    }
}

extern "C" void kernel_launch(void* const* d_in, const int* in_sizes, int n_in,
                              void* d_out, int out_size, void* d_ws, size_t ws_size,
                              hipStream_t stream) {
    const float* x    = (const float*)d_in[0];   // [B,S,IN] f32
    const float* w    = (const float*)d_in[1];   // [OUT,IN] f32 (e4m3-exact values)
    const float* bias = (const float*)d_in[2];   // [OUT]
    const float* in_s = (const float*)d_in[3];   // [1]
    const float* w_s  = (const float*)d_in[4];   // [1]
    float* out = (float*)d_out;                  // [B,S,OUT]

    const int  N   = in_sizes[2];                // 4096
    const long wsz = (long)in_sizes[1];
    const int  K   = (int)(wsz / N);             // 4096
    const long xsz = (long)in_sizes[0];
    const int  M   = (int)(xsz / K);             // 8192

    unsigned char* xq = (unsigned char*)d_ws;    // M*K e4m3 bytes
    unsigned char* wq = xq + (size_t)M * K;      // N*K e4m3 bytes

    quant_x_kernel<<<2048, 256, 0, stream>>>((const float4v*)x, (u32x4*)xq, in_s, xsz / 16);
    quant_w_kernel<<<2048, 256, 0, stream>>>((const float4v*)w, (u32x4*)wq, wsz / 16);

    dim3 grid((M / BM) * (N / BN));              // 32*16 = 512 blocks, %8==0
    gemm_kernel<<<grid, 512, 0, stream>>>(xq, wq, bias, in_s, w_s, out, M, N, K);
}

// Round 6
// 288.719 us; speedup vs baseline: 1.1011x; 1.1011x over previous
//
#include <hip/hip_runtime.h>
#include <stdint.h>

typedef float  f32x4  __attribute__((ext_vector_type(4)));
typedef float  float4v __attribute__((ext_vector_type(4)));
typedef int    i32x4  __attribute__((ext_vector_type(4)));
typedef int    i32x8  __attribute__((ext_vector_type(8)));
typedef unsigned int u32x4 __attribute__((ext_vector_type(4)));

#define BM 256
#define BN 128
#define BKB 128   // fp8 bytes (=elements) per K-step

// ---- f32 (pre-clamped to [-448,448]) -> OCP e4m3fn byte, RNE (matches ml_dtypes) ----
__device__ __forceinline__ unsigned f32_to_e4m3(float t) {
    unsigned u = __float_as_uint(t);
    unsigned s = (u >> 24) & 0x80u;
    float ax = fabsf(t);
    if (ax < 0.015625f) {                      // subnormal grid 2^-9
        int m = (int)rintf(ax * 512.0f);
        return s | (unsigned)m;
    }
    unsigned au = u & 0x7fffffffu;
    unsigned r = au + 0x7FFFFu + ((au >> 20) & 1u);   // RNE into top-3 mantissa bits
    return s | (((r >> 23) - 120u) << 3) | ((r >> 20) & 7u);
}

__global__ void quant_x_kernel(const float4v* __restrict__ x, u32x4* __restrict__ out,
                               const float* __restrict__ in_scale, long n16) {
    const float inv = 1.0f / in_scale[0];
    long i = (long)blockIdx.x * blockDim.x + threadIdx.x;
    const long stride = (long)gridDim.x * blockDim.x;
    for (; i < n16; i += stride) {
        u32x4 q;
#pragma unroll
        for (int j = 0; j < 4; ++j) {
            float4v v = x[i * 4 + j];
            unsigned p = 0;
#pragma unroll
            for (int e = 0; e < 4; ++e) {
                float t = fminf(fmaxf(v[e] * inv, -448.0f), 448.0f);
                p |= f32_to_e4m3(t) << (8 * e);
            }
            q[j] = p;
        }
        out[i] = q;
    }
}

__global__ void quant_w_kernel(const float4v* __restrict__ w, u32x4* __restrict__ out, long n16) {
    long i = (long)blockIdx.x * blockDim.x + threadIdx.x;
    const long stride = (long)gridDim.x * blockDim.x;
    for (; i < n16; i += stride) {
        u32x4 q;
#pragma unroll
        for (int j = 0; j < 4; ++j) {
            float4v v = w[i * 4 + j];
            unsigned p = 0;
#pragma unroll
            for (int e = 0; e < 4; ++e) p |= f32_to_e4m3(v[e]) << (8 * e);
            q[j] = p;
        }
        out[i] = q;
    }
}

// ============ 256x128 MX-fp8 GEMM, 3-deep counted-vmcnt pipeline (T3/T4) ============
// 8 waves (4M x 2N), per-wave 64x64 output (4x4 fragments, 64 acc regs).
// LDS: 3 x (A 32KB + B 16KB) = 144 KB. One s_barrier per K-tile; vmcnt never
// drains to 0 in the main loop (counted: leave next tile's 6 loads in flight).

__global__ __launch_bounds__(512, 2) void gemm_kernel(
    const unsigned char* __restrict__ A,   // [M,K] e4m3 bytes
    const unsigned char* __restrict__ W,   // [N,K] e4m3 bytes
    const float* __restrict__ bias,
    const float* __restrict__ in_scale,
    const float* __restrict__ w_scale,
    float* __restrict__ C, int M, int N, int K)
{
    __shared__ __align__(16) unsigned char sA[3][BM * BKB];  // 3 x 32 KB
    __shared__ __align__(16) unsigned char sB[3][BN * BKB];  // 3 x 16 KB

    const int tid  = threadIdx.x;
    const int wave = tid >> 6;     // 0..7
    const int lane = tid & 63;
    const int wr   = wave >> 1;    // 0..3  (M quarter, 64 rows)
    const int wc   = wave & 1;     // 0..1  (N half, 64 cols)

    // XCD-aware bijective swizzle (1024 % 8 == 0)
    const int nwg = gridDim.x;
    int bid = blockIdx.x, wgid;
    if ((nwg & 7) == 0) { const int cpx = nwg >> 3; wgid = (bid & 7) * cpx + (bid >> 3); }
    else wgid = bid;
    const int ntn  = N / BN;
    const int brow = (wgid / ntn) * BM;
    const int bcol = (wgid % ntn) * BN;

    // staging: chunks of 1KB (8 rows x 128B). A: 32 chunks (4/wave), B: 16 (2/wave).
    // phys 16B-slot (lane&7) holds logical slot (lane&7)^(lane>>3) (pre-swizzled source)
    const int rowInChunk = lane >> 3;
    const int slotLog    = (lane & 7) ^ rowInChunk;

    f32x4 acc[4][4];
#pragma unroll
    for (int i = 0; i < 4; ++i)
#pragma unroll
        for (int j = 0; j < 4; ++j) { f32x4 z = {0.f,0.f,0.f,0.f}; acc[i][j] = z; }

    const int g = lane >> 4;       // k-group: covers k bytes [g*32, g*32+32)

    const int NT = K / BKB;        // 32

    // 6 global_load_lds per thread per tile (A:4, B:2), oldest-first ordering
#define STAGE(bi, t)                                                              \
    {                                                                             \
        const int kt = (t) * BKB;                                                 \
        _Pragma("unroll")                                                         \
        for (int c = 0; c < 4; ++c) {                                             \
            const int chunk = wave * 4 + c;                                       \
            const int row   = chunk * 8 + rowInChunk;                             \
            const unsigned char* ga = A + (long)(brow + row) * K + kt + slotLog * 16; \
            __builtin_amdgcn_global_load_lds(                                     \
                (const __attribute__((address_space(1))) unsigned int*)ga,        \
                (__attribute__((address_space(3))) unsigned int*)(sA[bi] + chunk * 1024), 16, 0, 0); \
        }                                                                         \
        _Pragma("unroll")                                                         \
        for (int c = 0; c < 2; ++c) {                                             \
            const int chunk = wave * 2 + c;                                       \
            const int row   = chunk * 8 + rowInChunk;                             \
            const unsigned char* gb = W + (long)(bcol + row) * K + kt + slotLog * 16; \
            __builtin_amdgcn_global_load_lds(                                     \
                (const __attribute__((address_space(1))) unsigned int*)gb,        \
                (__attribute__((address_space(3))) unsigned int*)(sB[bi] + chunk * 1024), 16, 0, 0); \
        }                                                                         \
    }

    // 24 ds_read_b128 + 16 MFMA per wave
#define COMPUTE(bi)                                                               \
    {                                                                             \
        i32x8 bfr[4];                                                             \
        _Pragma("unroll")                                                         \
        for (int ni = 0; ni < 4; ++ni) {                                          \
            const int row = wc * 64 + ni * 16 + (lane & 15);                      \
            const int s0  = (g << 1) ^ (row & 7);                                 \
            i32x4 lo = *(const i32x4*)(sB[bi] + row * 128 + s0 * 16);             \
            i32x4 hi = *(const i32x4*)(sB[bi] + row * 128 + (s0 ^ 1) * 16);       \
            i32x8 tv;                                                             \
            tv[0]=lo[0]; tv[1]=lo[1]; tv[2]=lo[2]; tv[3]=lo[3];                   \
            tv[4]=hi[0]; tv[5]=hi[1]; tv[6]=hi[2]; tv[7]=hi[3];                   \
            bfr[ni] = tv;                                                         \
        }                                                                         \
        _Pragma("unroll")                                                         \
        for (int mi = 0; mi < 4; ++mi) {                                          \
            const int row = wr * 64 + mi * 16 + (lane & 15);                      \
            const int s0  = (g << 1) ^ (row & 7);                                 \
            i32x4 lo = *(const i32x4*)(sA[bi] + row * 128 + s0 * 16);             \
            i32x4 hi = *(const i32x4*)(sA[bi] + row * 128 + (s0 ^ 1) * 16);       \
            i32x8 av;                                                             \
            av[0]=lo[0]; av[1]=lo[1]; av[2]=lo[2]; av[3]=lo[3];                   \
            av[4]=hi[0]; av[5]=hi[1]; av[6]=hi[2]; av[7]=hi[3];                   \
            _Pragma("unroll")                                                     \
            for (int ni = 0; ni < 4; ++ni)                                        \
                acc[mi][ni] = __builtin_amdgcn_mfma_scale_f32_16x16x128_f8f6f4(   \
                    av, bfr[ni], acc[mi][ni],                                     \
                    0, 0, 0, 0x7F7F7F7F, 0, 0x7F7F7F7F);                          \
        }                                                                         \
    }

    // prologue: tiles 0,1 in flight (12 loads/thread)
    STAGE(0, 0);
    STAGE(1, 1);

    for (int t = 0; t < NT; ++t) {
        // counted drain: wait tile t's 6 loads; keep tile t+1's 6 in flight
        if (t < NT - 1) {
            asm volatile("s_waitcnt vmcnt(6) lgkmcnt(0)" ::: "memory");
        } else {
            asm volatile("s_waitcnt vmcnt(0) lgkmcnt(0)" ::: "memory");
        }
        __builtin_amdgcn_s_barrier();      // tile t fully in LDS; buf[(t+2)%3] readers done
        if (t + 2 < NT) STAGE((t + 2) % 3, t + 2);
        COMPUTE(t % 3);
    }
#undef STAGE
#undef COMPUTE

    // epilogue: out = acc * (s_in*s_w) + bias   (C/D: col=lane&15, row=(lane>>4)*4+r)
    const float sc = in_scale[0] * w_scale[0];
#pragma unroll
    for (int ni = 0; ni < 4; ++ni) {
        const int n   = bcol + wc * 64 + ni * 16 + (lane & 15);
        const float bv = bias[n];
#pragma unroll
        for (int mi = 0; mi < 4; ++mi) {
            const int m0 = brow + wr * 64 + mi * 16 + ((lane >> 4) << 2);
#pragma unroll
            for (int r = 0; r < 4; ++r)
                C[(long)(m0 + r) * N + n] = fmaf(acc[mi][ni][r], sc, bv);
        }
    }
}

extern "C" void kernel_launch(void* const* d_in, const int* in_sizes, int n_in,
                              void* d_out, int out_size, void* d_ws, size_t ws_size,
                              hipStream_t stream) {
    const float* x    = (const float*)d_in[0];   // [B,S,IN] f32
    const float* w    = (const float*)d_in[1];   // [OUT,IN] f32 (e4m3-exact values)
    const float* bias = (const float*)d_in[2];   // [OUT]
    const float* in_s = (const float*)d_in[3];   // [1]
    const float* w_s  = (const float*)d_in[4];   // [1]
    float* out = (float*)d_out;                  // [B,S,OUT]

    const int  N   = in_sizes[2];                // 4096
    const long wsz = (long)in_sizes[1];
    const int  K   = (int)(wsz / N);             // 4096
    const long xsz = (long)in_sizes[0];
    const int  M   = (int)(xsz / K);             // 8192

    unsigned char* xq = (unsigned char*)d_ws;    // M*K e4m3 bytes
    unsigned char* wq = xq + (size_t)M * K;      // N*K e4m3 bytes

    quant_x_kernel<<<2048, 256, 0, stream>>>((const float4v*)x, (u32x4*)xq, in_s, xsz / 16);
    quant_w_kernel<<<2048, 256, 0, stream>>>((const float4v*)w, (u32x4*)wq, wsz / 16);

    dim3 grid((M / BM) * (N / BN));              // 32*32 = 1024 blocks, %8==0
    gemm_kernel<<<grid, 512, 0, stream>>>(xq, wq, bias, in_s, w_s, out, M, N, K);
}

// Round 7
// 215.495 us; speedup vs baseline: 1.4753x; 1.3398x over previous
//
#include <hip/hip_runtime.h>
#include <stdint.h>

typedef float  f32x4  __attribute__((ext_vector_type(4)));
typedef float  float4v __attribute__((ext_vector_type(4)));
typedef int    i32x4  __attribute__((ext_vector_type(4)));
typedef int    i32x8  __attribute__((ext_vector_type(8)));
typedef unsigned int u32x4 __attribute__((ext_vector_type(4)));

#define BM 128
#define BN 128
#define BKB 256   // fp8 bytes per barrier-pair (2 x 128-byte half-tiles)

// ---- f32 (pre-clamped to [-448,448]) -> OCP e4m3fn byte, RNE (matches ml_dtypes) ----
__device__ __forceinline__ unsigned f32_to_e4m3(float t) {
    unsigned u = __float_as_uint(t);
    unsigned s = (u >> 24) & 0x80u;
    float ax = fabsf(t);
    if (ax < 0.015625f) {                      // subnormal grid 2^-9
        int m = (int)rintf(ax * 512.0f);
        return s | (unsigned)m;
    }
    unsigned au = u & 0x7fffffffu;
    unsigned r = au + 0x7FFFFu + ((au >> 20) & 1u);   // RNE into top-3 mantissa bits
    return s | (((r >> 23) - 120u) << 3) | ((r >> 20) & 7u);
}

__global__ void quant_x_kernel(const float4v* __restrict__ x, u32x4* __restrict__ out,
                               const float* __restrict__ in_scale, long n16) {
    const float inv = 1.0f / in_scale[0];
    long i = (long)blockIdx.x * blockDim.x + threadIdx.x;
    const long stride = (long)gridDim.x * blockDim.x;
    for (; i < n16; i += stride) {
        u32x4 q;
#pragma unroll
        for (int j = 0; j < 4; ++j) {
            float4v v = x[i * 4 + j];
            unsigned p = 0;
#pragma unroll
            for (int e = 0; e < 4; ++e) {
                float t = fminf(fmaxf(v[e] * inv, -448.0f), 448.0f);
                p |= f32_to_e4m3(t) << (8 * e);
            }
            q[j] = p;
        }
        out[i] = q;
    }
}

__global__ void quant_w_kernel(const float4v* __restrict__ w, u32x4* __restrict__ out, long n16) {
    long i = (long)blockIdx.x * blockDim.x + threadIdx.x;
    const long stride = (long)gridDim.x * blockDim.x;
    for (; i < n16; i += stride) {
        u32x4 q;
#pragma unroll
        for (int j = 0; j < 4; ++j) {
            float4v v = w[i * 4 + j];
            unsigned p = 0;
#pragma unroll
            for (int e = 0; e < 4; ++e) p |= f32_to_e4m3(v[e]) << (8 * e);
            q[j] = p;
        }
        out[i] = q;
    }
}

// ======= 128x128 MX-fp8 GEMM, R4 structure with BK=256 (2 half-tiles / barrier) =======
// 4 waves (2M x 2N), per-wave 64x64. LDS 64 KB -> 2 blocks/CU (the R4 co-residency).
// Per iter: stage 12 loads (2 half-tiles) -> barrier -> 32 MFMA/wave. 16 iters total.

__global__ __launch_bounds__(256, 2) void gemm_kernel(
    const unsigned char* __restrict__ A,   // [M,K] e4m3 bytes
    const unsigned char* __restrict__ W,   // [N,K] e4m3 bytes
    const float* __restrict__ bias,
    const float* __restrict__ in_scale,
    const float* __restrict__ w_scale,
    float* __restrict__ C, int M, int N, int K)
{
    __shared__ __align__(16) unsigned char sA0[BM * 128];  // 16 KB each
    __shared__ __align__(16) unsigned char sB0[BN * 128];
    __shared__ __align__(16) unsigned char sA1[BM * 128];
    __shared__ __align__(16) unsigned char sB1[BN * 128];

    const int tid  = threadIdx.x;
    const int wave = tid >> 6;
    const int lane = tid & 63;
    const int wr   = wave >> 1;
    const int wc   = wave & 1;

    // XCD-aware bijective swizzle (2048 % 8 == 0)
    const int nwg = gridDim.x;
    int bid = blockIdx.x, wgid;
    if ((nwg & 7) == 0) { const int cpx = nwg >> 3; wgid = (bid & 7) * cpx + (bid >> 3); }
    else wgid = bid;
    const int ntn  = N / BN;
    const int brow = (wgid / ntn) * BM;
    const int bcol = (wgid % ntn) * BN;

    // staging: 16 chunks of 1KB per half-tile (8 rows x 128B); wave stages chunks 4w..4w+3
    // phys 16B-slot (lane&7) holds logical slot (lane&7)^(lane>>3) (pre-swizzled source)
    const int rowInChunk = lane >> 3;
    const int slotLog    = (lane & 7) ^ rowInChunk;

    f32x4 acc[4][4];
#pragma unroll
    for (int i = 0; i < 4; ++i)
#pragma unroll
        for (int j = 0; j < 4; ++j) { f32x4 z = {0.f,0.f,0.f,0.f}; acc[i][j] = z; }

    const int g = lane >> 4;   // k-group: covers k bytes [g*32, g*32+32) within a half-tile

#define STAGE(dA, dB, kt)                                                         \
    {                                                                             \
        _Pragma("unroll")                                                         \
        for (int c = 0; c < 4; ++c) {                                             \
            const int chunk = wave * 4 + c;                                       \
            const int row   = chunk * 8 + rowInChunk;                             \
            const unsigned char* ga = A + (long)(brow + row) * K + (kt) + slotLog * 16; \
            const unsigned char* gb = W + (long)(bcol + row) * K + (kt) + slotLog * 16; \
            __builtin_amdgcn_global_load_lds(                                     \
                (const __attribute__((address_space(1))) unsigned int*)ga,        \
                (__attribute__((address_space(3))) unsigned int*)((dA) + chunk * 1024), 16, 0, 0); \
            __builtin_amdgcn_global_load_lds(                                     \
                (const __attribute__((address_space(1))) unsigned int*)gb,        \
                (__attribute__((address_space(3))) unsigned int*)((dB) + chunk * 1024), 16, 0, 0); \
        }                                                                         \
    }

#define COMPUTE(srcA, srcB)                                                       \
    {                                                                             \
        i32x8 af[4], bfr[4];                                                      \
        _Pragma("unroll")                                                         \
        for (int mi = 0; mi < 4; ++mi) {                                          \
            const int row = wr * 64 + mi * 16 + (lane & 15);                      \
            const int s0  = (g << 1) ^ (row & 7);                                 \
            i32x4 lo = *(const i32x4*)((srcA) + row * 128 + s0 * 16);             \
            i32x4 hi = *(const i32x4*)((srcA) + row * 128 + (s0 ^ 1) * 16);       \
            i32x8 tv;                                                             \
            tv[0]=lo[0]; tv[1]=lo[1]; tv[2]=lo[2]; tv[3]=lo[3];                   \
            tv[4]=hi[0]; tv[5]=hi[1]; tv[6]=hi[2]; tv[7]=hi[3];                   \
            af[mi] = tv;                                                          \
        }                                                                         \
        _Pragma("unroll")                                                         \
        for (int ni = 0; ni < 4; ++ni) {                                          \
            const int row = wc * 64 + ni * 16 + (lane & 15);                      \
            const int s0  = (g << 1) ^ (row & 7);                                 \
            i32x4 lo = *(const i32x4*)((srcB) + row * 128 + s0 * 16);             \
            i32x4 hi = *(const i32x4*)((srcB) + row * 128 + (s0 ^ 1) * 16);       \
            i32x8 tv;                                                             \
            tv[0]=lo[0]; tv[1]=lo[1]; tv[2]=lo[2]; tv[3]=lo[3];                   \
            tv[4]=hi[0]; tv[5]=hi[1]; tv[6]=hi[2]; tv[7]=hi[3];                   \
            bfr[ni] = tv;                                                         \
        }                                                                         \
        _Pragma("unroll")                                                         \
        for (int mi = 0; mi < 4; ++mi)                                            \
            _Pragma("unroll")                                                     \
            for (int ni = 0; ni < 4; ++ni)                                        \
                acc[mi][ni] = __builtin_amdgcn_mfma_scale_f32_16x16x128_f8f6f4(   \
                    af[mi], bfr[ni], acc[mi][ni],                                 \
                    0, 0, 0, 0x7F7F7F7F, 0, 0x7F7F7F7F);                          \
    }

    for (int kt = 0; kt < K; kt += BKB) {
        if (kt) __syncthreads();
        STAGE(sA0, sB0, kt);
        STAGE(sA1, sB1, kt + 128);
        __syncthreads();                 // compiler-emitted vmcnt(0): both half-tiles landed
        COMPUTE(sA0, sB0);
        COMPUTE(sA1, sB1);
    }
#undef STAGE
#undef COMPUTE

    // epilogue: out = acc * (s_in*s_w) + bias   (C/D: col=lane&15, row=(lane>>4)*4+r)
    const float sc = in_scale[0] * w_scale[0];
#pragma unroll
    for (int ni = 0; ni < 4; ++ni) {
        const int n   = bcol + wc * 64 + ni * 16 + (lane & 15);
        const float bv = bias[n];
#pragma unroll
        for (int mi = 0; mi < 4; ++mi) {
            const int m0 = brow + wr * 64 + mi * 16 + ((lane >> 4) << 2);
#pragma unroll
            for (int r = 0; r < 4; ++r)
                C[(long)(m0 + r) * N + n] = fmaf(acc[mi][ni][r], sc, bv);
        }
    }
}

extern "C" void kernel_launch(void* const* d_in, const int* in_sizes, int n_in,
                              void* d_out, int out_size, void* d_ws, size_t ws_size,
                              hipStream_t stream) {
    const float* x    = (const float*)d_in[0];   // [B,S,IN] f32
    const float* w    = (const float*)d_in[1];   // [OUT,IN] f32 (e4m3-exact values)
    const float* bias = (const float*)d_in[2];   // [OUT]
    const float* in_s = (const float*)d_in[3];   // [1]
    const float* w_s  = (const float*)d_in[4];   // [1]
    float* out = (float*)d_out;                  // [B,S,OUT]

    const int  N   = in_sizes[2];                // 4096
    const long wsz = (long)in_sizes[1];
    const int  K   = (int)(wsz / N);             // 4096
    const long xsz = (long)in_sizes[0];
    const int  M   = (int)(xsz / K);             // 8192

    unsigned char* xq = (unsigned char*)d_ws;    // M*K e4m3 bytes
    unsigned char* wq = xq + (size_t)M * K;      // N*K e4m3 bytes

    quant_x_kernel<<<2048, 256, 0, stream>>>((const float4v*)x, (u32x4*)xq, in_s, xsz / 16);
    quant_w_kernel<<<2048, 256, 0, stream>>>((const float4v*)w, (u32x4*)wq, wsz / 16);

    dim3 grid((M / BM) * (N / BN));              // 64*32 = 2048 blocks, %8==0
    gemm_kernel<<<grid, 256, 0, stream>>>(xq, wq, bias, in_s, w_s, out, M, N, K);
}